// Round 1
// baseline (2271.980 us; speedup 1.0000x reference)
//
#include <hip/hip_runtime.h>

#define HID 32
#define TLEN 512

__device__ __forceinline__ float sigmoidf_(float x) {
    return 1.0f / (1.0f + __expf(-x));
}
// tanh via exp, saturates correctly at +/-1 for large |x| (no inf/inf NaN)
__device__ __forceinline__ float tanhf_(float x) {
    return 1.0f - 2.0f / (__expf(2.0f * x) + 1.0f);
}

__global__ __launch_bounds__(192, 2)
void lstm2_kernel(const float* __restrict__ x,
                  const float* __restrict__ w_ih0,
                  const float* __restrict__ w_hh0,
                  const float* __restrict__ b_ih0,
                  const float* __restrict__ b_hh0,
                  const float* __restrict__ w_ih1,
                  const float* __restrict__ w_hh1,
                  const float* __restrict__ b_ih1,
                  const float* __restrict__ b_hh1,
                  const float* __restrict__ fc1_w,
                  const float* __restrict__ fc1_b,
                  const float* __restrict__ fc2_w,
                  const float* __restrict__ fc2_b,
                  float* __restrict__ out)
{
    // Per-WG: 2 batch elements, 3 waves.
    // wave 0: layer0 recurrence matvec + NL + (c0,h0) state
    // wave 2: p2 = w_hh1 . h1_{t-1}
    // wave 1: gates1 = w_ih1 . h0_t + p2 + bias -> NL -> (c1,h1) state
    __shared__ float x_lds[2 * TLEN];     // [2][512]
    __shared__ float h0buf[2][HID];
    __shared__ float h1buf[2][HID];
    __shared__ float p2buf[2][4 * HID];
    __shared__ float red[2][16];

    const int tid  = threadIdx.x;
    const int wid  = tid >> 6;
    const int lane = tid & 63;
    const int half = lane >> 5;   // which of the 2 batch elements
    const int j    = lane & 31;   // hidden unit owned by this lane
    const long b0  = (long)blockIdx.x * 2;

    // stage x[b0..b0+1][0..511] into LDS (contiguous, coalesced)
    for (int i = tid; i < 2 * TLEN; i += 192) {
        x_lds[i] = x[b0 * TLEN + i];
    }
    if (tid < 64) {
        ((float*)h0buf)[tid] = 0.0f;
        ((float*)h1buf)[tid] = 0.0f;
    }

    // per-wave weight rows in registers: rows {j, j+32, j+64, j+96}
    const float* wmat = (wid == 0) ? w_hh0 : ((wid == 1) ? w_ih1 : w_hh1);
    float wr[4][32];
    float bias4[4];
    float xw4[4];
    #pragma unroll
    for (int g = 0; g < 4; ++g) {
        const int row = j + 32 * g;
        #pragma unroll
        for (int q = 0; q < 8; ++q) {
            float4 v = *(const float4*)(wmat + row * 32 + 4 * q);
            wr[g][4 * q + 0] = v.x;
            wr[g][4 * q + 1] = v.y;
            wr[g][4 * q + 2] = v.z;
            wr[g][4 * q + 3] = v.w;
        }
        if (wid == 0) { bias4[g] = b_ih0[row] + b_hh0[row]; xw4[g] = w_ih0[row]; }
        else if (wid == 1) { bias4[g] = b_ih1[row] + b_hh1[row]; xw4[g] = 0.0f; }
        else { bias4[g] = 0.0f; xw4[g] = 0.0f; }
    }

    float c_state = 0.0f;   // c0 for wave0 lanes, c1 for wave1 lanes
    __syncthreads();

    for (int t = 0; t < TLEN; ++t) {
        // ---- phase A: wave0 (layer0 full step), wave2 (h1 recurrence matvec)
        if (wid == 0) {
            float hreg[32];
            #pragma unroll
            for (int q = 0; q < 8; ++q) {
                float4 v = *(const float4*)&h0buf[half][4 * q];  // uniform-per-half broadcast
                hreg[4 * q + 0] = v.x; hreg[4 * q + 1] = v.y;
                hreg[4 * q + 2] = v.z; hreg[4 * q + 3] = v.w;
            }
            const float xt = x_lds[half * TLEN + t];
            float acc[4];
            #pragma unroll
            for (int g = 0; g < 4; ++g) acc[g] = xt * xw4[g] + bias4[g];
            #pragma unroll
            for (int k = 0; k < 32; ++k) {
                #pragma unroll
                for (int g = 0; g < 4; ++g) acc[g] += wr[g][k] * hreg[k];
            }
            const float ig = sigmoidf_(acc[0]);
            const float fg = sigmoidf_(acc[1]);
            const float gg = tanhf_(acc[2]);
            const float og = sigmoidf_(acc[3]);
            c_state = fg * c_state + ig * gg;
            const float hnew = og * tanhf_(c_state);
            h0buf[half][j] = hnew;   // data-dependent on all reads -> no WAR hazard
        } else if (wid == 2) {
            float hreg[32];
            #pragma unroll
            for (int q = 0; q < 8; ++q) {
                float4 v = *(const float4*)&h1buf[half][4 * q];
                hreg[4 * q + 0] = v.x; hreg[4 * q + 1] = v.y;
                hreg[4 * q + 2] = v.z; hreg[4 * q + 3] = v.w;
            }
            float acc[4] = {0.0f, 0.0f, 0.0f, 0.0f};
            #pragma unroll
            for (int k = 0; k < 32; ++k) {
                #pragma unroll
                for (int g = 0; g < 4; ++g) acc[g] += wr[g][k] * hreg[k];
            }
            #pragma unroll
            for (int g = 0; g < 4; ++g) p2buf[half][j + 32 * g] = acc[g];
        }
        __syncthreads();
        // ---- phase B: wave1 (layer1 input matvec + combine + NL + state)
        if (wid == 1) {
            float hreg[32];
            #pragma unroll
            for (int q = 0; q < 8; ++q) {
                float4 v = *(const float4*)&h0buf[half][4 * q];
                hreg[4 * q + 0] = v.x; hreg[4 * q + 1] = v.y;
                hreg[4 * q + 2] = v.z; hreg[4 * q + 3] = v.w;
            }
            float acc[4];
            #pragma unroll
            for (int g = 0; g < 4; ++g) acc[g] = bias4[g] + p2buf[half][j + 32 * g];
            #pragma unroll
            for (int k = 0; k < 32; ++k) {
                #pragma unroll
                for (int g = 0; g < 4; ++g) acc[g] += wr[g][k] * hreg[k];
            }
            const float ig = sigmoidf_(acc[0]);
            const float fg = sigmoidf_(acc[1]);
            const float gg = tanhf_(acc[2]);
            const float og = sigmoidf_(acc[3]);
            c_state = fg * c_state + ig * gg;
            const float hnew = og * tanhf_(c_state);
            h1buf[half][j] = hnew;
        }
        __syncthreads();
    }

    // ---- head: fc2( relu( fc1 . h1_T ) ), done by wave 0
    if (wid == 0 && j < 16) {
        float acc = fc1_b[j];
        #pragma unroll
        for (int q = 0; q < 8; ++q) {
            float4 w = *(const float4*)(fc1_w + j * 32 + 4 * q);
            float4 hv = *(const float4*)&h1buf[half][4 * q];
            acc += w.x * hv.x + w.y * hv.y + w.z * hv.z + w.w * hv.w;
        }
        red[half][j] = fmaxf(acc, 0.0f);
    }
    __syncthreads();
    if (wid == 0 && j == 0) {
        float acc = fc2_b[0];
        #pragma unroll
        for (int r = 0; r < 16; ++r) acc += fc2_w[r] * red[half][r];
        out[b0 + half] = acc;
    }
}

extern "C" void kernel_launch(void* const* d_in, const int* in_sizes, int n_in,
                              void* d_out, int out_size, void* d_ws, size_t ws_size,
                              hipStream_t stream) {
    const float* x     = (const float*)d_in[0];
    const float* w_ih0 = (const float*)d_in[1];
    const float* w_hh0 = (const float*)d_in[2];
    const float* b_ih0 = (const float*)d_in[3];
    const float* b_hh0 = (const float*)d_in[4];
    const float* w_ih1 = (const float*)d_in[5];
    const float* w_hh1 = (const float*)d_in[6];
    const float* b_ih1 = (const float*)d_in[7];
    const float* b_hh1 = (const float*)d_in[8];
    const float* fc1_w = (const float*)d_in[9];
    const float* fc1_b = (const float*)d_in[10];
    const float* fc2_w = (const float*)d_in[11];
    const float* fc2_b = (const float*)d_in[12];
    float* out = (float*)d_out;

    const int B = 4096;
    dim3 grid(B / 2);
    dim3 block(192);
    hipLaunchKernelGGL(lstm2_kernel, grid, block, 0, stream,
                       x, w_ih0, w_hh0, b_ih0, b_hh0,
                       w_ih1, w_hh1, b_ih1, b_hh1,
                       fc1_w, fc1_b, fc2_w, fc2_b, out);
}

// Round 2
// 1518.058 us; speedup vs baseline: 1.4966x; 1.4966x over previous
//
#include <hip/hip_runtime.h>

#define TLEN 512

__device__ __forceinline__ float sigmoidf_(float x) {
    return 1.0f / (1.0f + __expf(-x));
}
// tanh via exp, saturates correctly for large |x|
__device__ __forceinline__ float tanhf_(float x) {
    return 1.0f - 2.0f / (__expf(2.0f * x) + 1.0f);
}

// One wave = one batch element. lane = gh*32 + j.
//  gh=0 lanes own rows {j, j+32}    = (i_j, f_j)
//  gh=1 lanes own rows {j+64, j+96} = (g_j, o_j)
// of each of the 3 recurrent/input matrices (w_hh0, w_ih1, w_hh1),
// kept in VGPRs (192 floats/lane). h broadcast via per-wave LDS (no barriers).
__global__ __launch_bounds__(256, 2)
void lstm2_kernel(const float* __restrict__ x,
                  const float* __restrict__ w_ih0,
                  const float* __restrict__ w_hh0,
                  const float* __restrict__ b_ih0,
                  const float* __restrict__ b_hh0,
                  const float* __restrict__ w_ih1,
                  const float* __restrict__ w_hh1,
                  const float* __restrict__ b_ih1,
                  const float* __restrict__ b_hh1,
                  const float* __restrict__ fc1_w,
                  const float* __restrict__ fc1_b,
                  const float* __restrict__ fc2_w,
                  const float* __restrict__ fc2_b,
                  float* __restrict__ out)
{
    __shared__ float x_lds[4][TLEN];
    __shared__ float hb0[4][32];
    __shared__ float hb1[4][32];

    const int tid  = threadIdx.x;
    const int wid  = tid >> 6;
    const int lane = tid & 63;
    const int gh   = lane >> 5;   // gate-half: 0 -> (i,f), 1 -> (g,o)
    const int j    = lane & 31;   // hidden unit
    const long b   = (long)blockIdx.x * 4 + wid;

    // stage this wave's x sequence (wave-private LDS region, no barrier needed)
    for (int i = lane; i < TLEN; i += 64) x_lds[wid][i] = x[b * TLEN + i];
    if (lane < 32) { hb0[wid][lane] = 0.0f; hb1[wid][lane] = 0.0f; }

    const int r0 = j + 64 * gh;
    const int r1 = r0 + 32;

    // weights in registers: 6 rows of 32
    float w00[32], w01[32], w10[32], w11[32], w20[32], w21[32];
    #pragma unroll
    for (int q = 0; q < 8; ++q) {
        float4 v;
        v = *(const float4*)(w_hh0 + r0 * 32 + 4 * q);
        w00[4*q] = v.x; w00[4*q+1] = v.y; w00[4*q+2] = v.z; w00[4*q+3] = v.w;
        v = *(const float4*)(w_hh0 + r1 * 32 + 4 * q);
        w01[4*q] = v.x; w01[4*q+1] = v.y; w01[4*q+2] = v.z; w01[4*q+3] = v.w;
        v = *(const float4*)(w_ih1 + r0 * 32 + 4 * q);
        w10[4*q] = v.x; w10[4*q+1] = v.y; w10[4*q+2] = v.z; w10[4*q+3] = v.w;
        v = *(const float4*)(w_ih1 + r1 * 32 + 4 * q);
        w11[4*q] = v.x; w11[4*q+1] = v.y; w11[4*q+2] = v.z; w11[4*q+3] = v.w;
        v = *(const float4*)(w_hh1 + r0 * 32 + 4 * q);
        w20[4*q] = v.x; w20[4*q+1] = v.y; w20[4*q+2] = v.z; w20[4*q+3] = v.w;
        v = *(const float4*)(w_hh1 + r1 * 32 + 4 * q);
        w21[4*q] = v.x; w21[4*q+1] = v.y; w21[4*q+2] = v.z; w21[4*q+3] = v.w;
    }

    const float xw0  = w_ih0[r0];
    const float xw1  = w_ih0[r1];
    const float bb00 = b_ih0[r0] + b_hh0[r0];
    const float bb01 = b_ih0[r1] + b_hh0[r1];
    const float bb10 = b_ih1[r0] + b_hh1[r0];
    const float bb11 = b_ih1[r1] + b_hh1[r1];

    const float ghf = (float)gh;          // 0.0 or 1.0
    const float sc  = 1.0f + ghf;         // 1 or 2 (tanh-via-sigmoid trick)

    float c0 = 0.0f, c1 = 0.0f;

    for (int t = 0; t < TLEN; ++t) {
        const float xt = x_lds[wid][t];
        float a00 = bb00 + xt * xw0;      // layer0 gate rows r0/r1
        float a01 = bb01 + xt * xw1;
        float a10 = 0.0f, a11 = 0.0f;     // w_hh1 . h1_prev part

        #pragma unroll
        for (int q = 0; q < 8; ++q) {
            float4 h0v = *(const float4*)&hb0[wid][4 * q];
            float4 h1v = *(const float4*)&hb1[wid][4 * q];
            a00 += w00[4*q]*h0v.x + w00[4*q+1]*h0v.y + w00[4*q+2]*h0v.z + w00[4*q+3]*h0v.w;
            a01 += w01[4*q]*h0v.x + w01[4*q+1]*h0v.y + w01[4*q+2]*h0v.z + w01[4*q+3]*h0v.w;
            a10 += w20[4*q]*h1v.x + w20[4*q+1]*h1v.y + w20[4*q+2]*h1v.z + w20[4*q+3]*h1v.w;
            a11 += w21[4*q]*h1v.x + w21[4*q+1]*h1v.y + w21[4*q+2]*h1v.z + w21[4*q+3]*h1v.w;
        }

        // ---- layer0 nonlinearity (branchless gate-type select) ----
        {
            float s  = sigmoidf_(a00 * sc);
            float v0 = s * sc - ghf;            // gh? tanh(a00) : sigmoid(a00)
            float v1 = sigmoidf_(a01);          // f (gh0) or o (gh1)
            float ov0 = __shfl_xor(v0, 32);
            float ov1 = __shfl_xor(v1, 32);
            float i_ = gh ? ov0 : v0;
            float f_ = gh ? ov1 : v1;
            float g_ = gh ? v0 : ov0;
            float o_ = gh ? v1 : ov1;
            c0 = f_ * c0 + i_ * g_;
            float h0 = o_ * tanhf_(c0);
            hb0[wid][j] = h0;                   // lanes j and j+32 write same value
        }

        // ---- layer1: w_ih1 . h0_new + (w_hh1 . h1_prev) ----
        float a10b = bb10 + a10;
        float a11b = bb11 + a11;
        #pragma unroll
        for (int q = 0; q < 8; ++q) {
            float4 hv = *(const float4*)&hb0[wid][4 * q];
            a10b += w10[4*q]*hv.x + w10[4*q+1]*hv.y + w10[4*q+2]*hv.z + w10[4*q+3]*hv.w;
            a11b += w11[4*q]*hv.x + w11[4*q+1]*hv.y + w11[4*q+2]*hv.z + w11[4*q+3]*hv.w;
        }
        {
            float s  = sigmoidf_(a10b * sc);
            float v0 = s * sc - ghf;
            float v1 = sigmoidf_(a11b);
            float ov0 = __shfl_xor(v0, 32);
            float ov1 = __shfl_xor(v1, 32);
            float i_ = gh ? ov0 : v0;
            float f_ = gh ? ov1 : v1;
            float g_ = gh ? v0 : ov0;
            float o_ = gh ? v1 : ov1;
            c1 = f_ * c1 + i_ * g_;
            float h1 = o_ * tanhf_(c1);
            hb1[wid][j] = h1;
        }
    }

    // ---- head: out[b] = fc2( relu( fc1 . h1_T ) ) ----
    {
        const int r = lane & 15;
        float acc = fc1_b[r];
        #pragma unroll
        for (int q = 0; q < 8; ++q) {
            float4 wv = *(const float4*)(fc1_w + r * 32 + 4 * q);
            float4 hv = *(const float4*)&hb1[wid][4 * q];
            acc += wv.x * hv.x + wv.y * hv.y + wv.z * hv.z + wv.w * hv.w;
        }
        acc = fmaxf(acc, 0.0f) * fc2_w[r];
        acc = (lane < 16) ? acc : 0.0f;
        acc += __shfl_xor(acc, 8);
        acc += __shfl_xor(acc, 4);
        acc += __shfl_xor(acc, 2);
        acc += __shfl_xor(acc, 1);
        if (lane == 0) out[b] = acc + fc2_b[0];
    }
}

extern "C" void kernel_launch(void* const* d_in, const int* in_sizes, int n_in,
                              void* d_out, int out_size, void* d_ws, size_t ws_size,
                              hipStream_t stream) {
    const float* x     = (const float*)d_in[0];
    const float* w_ih0 = (const float*)d_in[1];
    const float* w_hh0 = (const float*)d_in[2];
    const float* b_ih0 = (const float*)d_in[3];
    const float* b_hh0 = (const float*)d_in[4];
    const float* w_ih1 = (const float*)d_in[5];
    const float* w_hh1 = (const float*)d_in[6];
    const float* b_ih1 = (const float*)d_in[7];
    const float* b_hh1 = (const float*)d_in[8];
    const float* fc1_w = (const float*)d_in[9];
    const float* fc1_b = (const float*)d_in[10];
    const float* fc2_w = (const float*)d_in[11];
    const float* fc2_b = (const float*)d_in[12];
    float* out = (float*)d_out;

    const int B = 4096;
    dim3 grid(B / 4);     // 4 independent waves (batch elements) per block
    dim3 block(256);
    hipLaunchKernelGGL(lstm2_kernel, grid, block, 0, stream,
                       x, w_ih0, w_hh0, b_ih0, b_hh0,
                       w_ih1, w_hh1, b_ih1, b_hh1,
                       fc1_w, fc1_b, fc2_w, fc2_b, out);
}